// Round 3
// baseline (498.329 us; speedup 1.0000x reference)
//
#include <hip/hip_runtime.h>
#include <hip/hip_bf16.h>

#define N_    2
#define T_    7
#define C_    96
#define H_    96
#define W_    96
#define HW_   9216
#define HEAD_ 4
#define HD_   24
#define C3_   288
#define P_    32
#define QP_   97
#define CATP_ 292
#define NBLK_ (N_ * (HW_ / P_))          // 576
#define PERN_ ((size_t)T_ * C_ * HW_)    // elems per (tensor, one n) = 6,193,152

typedef unsigned int u32;
typedef unsigned short u16;

__device__ __forceinline__ float bits2f(u32 b) {
    union { u32 u; float f; } x; x.u = b; return x.f;
}

template<bool BF16>
__device__ __forceinline__ float ld1(const void* p, int i) {
    if constexpr (BF16) return bits2f(((u32)((const u16*)p)[i]) << 16);
    else                return ((const float*)p)[i];
}

template<bool BF16>
__device__ __forceinline__ void ld4w(const void* p, int i, float w[4]) {
    if constexpr (BF16) {
        const uint2 u = ((const uint2*)p)[i >> 2];
        w[0] = bits2f(u.x << 16);
        w[1] = bits2f(u.x & 0xFFFF0000u);
        w[2] = bits2f(u.y << 16);
        w[3] = bits2f(u.y & 0xFFFF0000u);
    } else {
        const float4 v = *((const float4*)((const float*)p + i));
        w[0] = v.x; w[1] = v.y; w[2] = v.z; w[3] = v.w;
    }
}

template<bool BF16>
__device__ __forceinline__ void st1(void* p, int i, float v) {
    if constexpr (BF16) ((__hip_bfloat16*)p)[i] = __float2bfloat16(v);
    else                ((float*)p)[i] = v;
}

__device__ __forceinline__ void unpack8(uint4 u, float f[8]) {
    f[0] = bits2f(u.x << 16); f[1] = bits2f(u.x & 0xFFFF0000u);
    f[2] = bits2f(u.y << 16); f[3] = bits2f(u.y & 0xFFFF0000u);
    f[4] = bits2f(u.z << 16); f[5] = bits2f(u.z & 0xFFFF0000u);
    f[6] = bits2f(u.w << 16); f[7] = bits2f(u.w & 0xFFFF0000u);
}

// ---- dtype detector (bf16 vs f32) ----
__global__ void detect_dtype_kernel(const u32* __restrict__ w, int* __restrict__ flag) {
    u32 x = w[threadIdx.x];
    u32 f = x & 0x7FFFu;
    int inwin = (f >= 0x3A00u) && (f <= 0x4200u);
    unsigned long long m = __ballot(inwin);
    if (threadIdx.x == 0) flag[0] = (__popcll(m) >= 40) ? 1 : 0;
}

// ---- transpose (n,t,c,hw) -> (nt,hw,c) into ws, bf16 only ----
// grid = n_tensors * n_count * T_ * 36, block 256 (1 thread = 1 pixel)
__global__ __launch_bounds__(256) void transpose_kernel(
    const u16* __restrict__ idxf, const u16* __restrict__ s1,
    const u16* __restrict__ s2, const u16* __restrict__ s3,
    u16* __restrict__ wsb, const int* __restrict__ flag,
    int n_tensors, int n_base, int n_count)
{
    if (*flag == 0) return;
    const int per_t = n_count * T_ * 36;
    int b = blockIdx.x;
    int tens = b / per_t;
    int rem  = b - tens * per_t;
    int nt   = rem / 36;            // local (n_off * T_ + t)
    int pb   = rem - nt * 36;
    const u16* src = (tens == 0) ? idxf : (tens == 1) ? s1 : (tens == 2) ? s2 : s3;
    int n_off = nt / T_, t = nt - n_off * T_;
    size_t bt_global = (size_t)(n_base + n_off) * T_ + t;
    int p = pb * 256 + threadIdx.x;
    const u16* sp = src + bt_global * (C_ * HW_) + p;
    u16* dp = wsb + (size_t)tens * ((size_t)n_count * PERN_) + ((size_t)nt * HW_ + p) * C_;
    #pragma unroll
    for (int v = 0; v < 12; ++v) {
        u32 a[8];
        #pragma unroll
        for (int j = 0; j < 8; ++j) a[j] = sp[(size_t)(8 * v + j) * HW_];
        uint4 u;
        u.x = a[0] | (a[1] << 16);
        u.y = a[2] | (a[3] << 16);
        u.z = a[4] | (a[5] << 16);
        u.w = a[6] | (a[7] << 16);
        ((uint4*)dp)[v] = u;
    }
}

// ---- optimized main kernel (bf16). PICKT: pick phase uses transposed s1..s3.
// grid = n_count * 288
template<int PICKT>
__global__ __launch_bounds__(256) void traj_opt(
    const u16* __restrict__ curr, const u16* __restrict__ anchor,
    const u16* __restrict__ loc, const u16* __restrict__ pw,
    const u16* __restrict__ pbias, const u16* __restrict__ fw,
    const u16* __restrict__ fbias, __hip_bfloat16* __restrict__ outp,
    const u16* __restrict__ wsb,
    const u16* __restrict__ s1o, const u16* __restrict__ s2o, const u16* __restrict__ s3o,
    const int* __restrict__ flag, int n_base, int n_count)
{
    if (*flag == 0) return;

    __shared__ __align__(16) char smem[31232];
    u16 (*s_k)[P_][C_]  = (u16(*)[P_][C_])smem;          // phase A: [2][32][96] = 12288 B
    u16* s_curr         = (u16*)(smem + 12288);          // phase A: [96*32]     = 6144 B
    u16 (*s_cat)[C3_]   = (u16(*)[C3_])smem;             // phase B: [32][288]   = 18432 B
    float (*s_mid)[100] = (float(*)[100])(smem + 18432); // phase B: [32][100]   = 12800 B
    __shared__ int   s_lin[T_][P_];
    __shared__ float s_soft[P_][HEAD_];
    __shared__ int   s_bidx[P_][HEAD_];

    const int tid = threadIdx.x;
    const int b   = blockIdx.x;
    const int nnl = b / (HW_ / P_);              // local n
    const int nn  = n_base + nnl;                // global n
    const int p0  = (b - nnl * (HW_ / P_)) * P_;
    const size_t tstride = (size_t)n_count * PERN_;

    // ---- nearest-sample indices (exact reference f32 op sequence) ----
    if (tid < T_ * P_) {
        int t = tid / P_, pp = tid - t * P_;
        int p = p0 + pp;
        float x = bits2f(((u32)loc[(nn * 2 * T_ + 2 * t    ) * HW_ + p]) << 16);
        float y = bits2f(((u32)loc[(nn * 2 * T_ + 2 * t + 1) * HW_ + p]) << 16);
        float gx = 2.0f * x / 95.0f - 1.0f;
        float gy = 2.0f * y / 95.0f - 1.0f;
        float fx = (gx + 1.0f) * 0.5f * 95.0f;
        float fy = (gy + 1.0f) * 0.5f * 95.0f;
        float ix = rintf(fx), iy = rintf(fy);
        bool v = (ix >= 0.0f) && (ix <= 95.0f) && (iy >= 0.0f) && (iy <= 95.0f);
        s_lin[t][pp] = v ? ((int)iy * W_ + (int)ix) : -1;
    }
    // ---- load curr tile (96 ch x 32 px, ch-major) ----
    for (int i = tid; i < C_ * 4; i += 256) {
        int ch = i >> 2, v = i & 3;
        const uint4 u = *((const uint4*)(curr + (size_t)(nn * C_ + ch) * HW_ + p0 + 8 * v));
        *((uint4*)&s_curr[ch * P_ + 8 * v]) = u;
    }
    __syncthreads();

    // ---- per (pixel, head) thread: q fragment, L2-normalized over full c ----
    const int pp = tid >> 2;
    const int hh = tid & 3;
    float qreg[HD_];
    float best = -3.0e38f;
    int   bidx = 0;
    if (tid < 128) {
        float ssq = 0.f;
        #pragma unroll
        for (int j = 0; j < HD_; ++j) {
            float v = bits2f(((u32)s_curr[(hh * HD_ + j) * P_ + pp]) << 16);
            qreg[j] = v;
            ssq += v * v;
        }
        ssq += __shfl_xor(ssq, 1);
        ssq += __shfl_xor(ssq, 2);
        float inv = 1.0f / fmaxf(sqrtf(ssq), 1e-12f);
        #pragma unroll
        for (int j = 0; j < HD_; ++j) qreg[j] *= inv;
    }

    const u16* widx = wsb;   // transposed index_feat
    auto gather_k = [&](int t, int buf) {
        for (int i = tid; i < P_ * 12; i += 256) {
            int gp = i / 12, v = i - gp * 12;
            int lin = s_lin[t][gp];
            uint4 u = make_uint4(0u, 0u, 0u, 0u);
            if (lin >= 0)
                u = *((const uint4*)(widx + ((size_t)(nnl * T_ + t) * HW_ + lin) * C_ + 8 * v));
            *((uint4*)&s_k[buf][gp][8 * v]) = u;
        }
    };

    gather_k(0, 0);
    __syncthreads();
    for (int t = 0; t < T_; ++t) {
        if (t + 1 < T_) gather_k(t + 1, (t + 1) & 1);
        if (tid < 128) {
            const uint4* kp = (const uint4*)&s_k[t & 1][pp][hh * HD_];
            float kv[HD_];
            unpack8(kp[0], kv);
            unpack8(kp[1], kv + 8);
            unpack8(kp[2], kv + 16);
            float ssq = 0.f, dot = 0.f;
            #pragma unroll
            for (int j = 0; j < HD_; ++j) { ssq += kv[j] * kv[j]; dot += kv[j] * qreg[j]; }
            ssq += __shfl_xor(ssq, 1);
            ssq += __shfl_xor(ssq, 2);
            float score = dot * (1.0f / fmaxf(sqrtf(ssq), 1e-12f));
            if (score > best) { best = score; bidx = t; }   // strict > == first-max
        }
        __syncthreads();
    }
    if (tid < 128) { s_soft[pp][hh] = best; s_bidx[pp][hh] = bidx; }
    __syncthreads();   // phase A ends; s_k/s_curr regions become s_cat

    // ---- gather winning frames into cat tile ----
    if constexpr (PICKT) {
        for (int i = tid; i < P_ * 36; i += 256) {
            int gp = i / 36, chunk = i - gp * 36;
            int d0 = chunk * 8;
            int set = d0 / C_, ch = d0 - set * C_;
            int h = ch / HD_;
            int bt = s_bidx[gp][h];
            int lin = s_lin[bt][gp];
            uint4 u = make_uint4(0u, 0u, 0u, 0u);
            if (lin >= 0)
                u = *((const uint4*)(wsb + (size_t)(1 + set) * tstride
                                     + ((size_t)(nnl * T_ + bt) * HW_ + lin) * C_ + ch));
            *((uint4*)&s_cat[gp][d0]) = u;
        }
    } else {
        for (int i = tid; i < P_ * C3_; i += 256) {
            int gp = i / C3_, d = i - gp * C3_;
            int set = d / C_, ch = d - set * C_;
            int h = ch / HD_;
            int bt = s_bidx[gp][h];
            int lin = s_lin[bt][gp];
            u16 v = 0;
            if (lin >= 0) {
                const u16* sp = (set == 0) ? s1o : (set == 1) ? s2o : s3o;
                v = sp[((size_t)(nn * T_ + bt) * C_ + ch) * HW_ + lin];
            }
            s_cat[gp][d] = v;
        }
    }
    __syncthreads();

    // ---- fusion GEMV (96 x 288) + bias, scaled by per-head max score ----
    for (int u = tid; u < 24 * P_; u += 256) {
        int cog = u / P_, gp = u - cog * P_;
        int co0 = cog * 4;
        float a0 = 0.f, a1 = 0.f, a2 = 0.f, a3 = 0.f;
        for (int d = 0; d < C3_; d += 8) {
            float cv[8], wv[8];
            unpack8(*((const uint4*)&s_cat[gp][d]), cv);
            unpack8(*((const uint4*)(fw + (co0 + 0) * C3_ + d)), wv);
            #pragma unroll
            for (int j = 0; j < 8; ++j) a0 += wv[j] * cv[j];
            unpack8(*((const uint4*)(fw + (co0 + 1) * C3_ + d)), wv);
            #pragma unroll
            for (int j = 0; j < 8; ++j) a1 += wv[j] * cv[j];
            unpack8(*((const uint4*)(fw + (co0 + 2) * C3_ + d)), wv);
            #pragma unroll
            for (int j = 0; j < 8; ++j) a2 += wv[j] * cv[j];
            unpack8(*((const uint4*)(fw + (co0 + 3) * C3_ + d)), wv);
            #pragma unroll
            for (int j = 0; j < 8; ++j) a3 += wv[j] * cv[j];
        }
        float soft = s_soft[gp][co0 / HD_];
        s_mid[gp][co0 + 0] = (a0 + bits2f(((u32)fbias[co0 + 0]) << 16)) * soft;
        s_mid[gp][co0 + 1] = (a1 + bits2f(((u32)fbias[co0 + 1]) << 16)) * soft;
        s_mid[gp][co0 + 2] = (a2 + bits2f(((u32)fbias[co0 + 2]) << 16)) * soft;
        s_mid[gp][co0 + 3] = (a3 + bits2f(((u32)fbias[co0 + 3]) << 16)) * soft;
    }
    __syncthreads();

    // ---- proj GEMV (96 x 96) + bias + anchor, store ----
    for (int u = tid; u < 24 * P_; u += 256) {
        int dog = u / P_, gp = u - dog * P_;
        int do0 = dog * 4;
        float a0 = 0.f, a1 = 0.f, a2 = 0.f, a3 = 0.f;
        for (int c = 0; c < C_; c += 8) {
            const float4 m0 = *((const float4*)&s_mid[gp][c]);
            const float4 m1 = *((const float4*)&s_mid[gp][c + 4]);
            float mv[8] = { m0.x, m0.y, m0.z, m0.w, m1.x, m1.y, m1.z, m1.w };
            float wv[8];
            unpack8(*((const uint4*)(pw + (do0 + 0) * C_ + c)), wv);
            #pragma unroll
            for (int j = 0; j < 8; ++j) a0 += wv[j] * mv[j];
            unpack8(*((const uint4*)(pw + (do0 + 1) * C_ + c)), wv);
            #pragma unroll
            for (int j = 0; j < 8; ++j) a1 += wv[j] * mv[j];
            unpack8(*((const uint4*)(pw + (do0 + 2) * C_ + c)), wv);
            #pragma unroll
            for (int j = 0; j < 8; ++j) a2 += wv[j] * mv[j];
            unpack8(*((const uint4*)(pw + (do0 + 3) * C_ + c)), wv);
            #pragma unroll
            for (int j = 0; j < 8; ++j) a3 += wv[j] * mv[j];
        }
        int p = p0 + gp;
        #pragma unroll
        for (int r = 0; r < 4; ++r) {
            float acc = (r == 0) ? a0 : (r == 1) ? a1 : (r == 2) ? a2 : a3;
            float res = acc + bits2f(((u32)pbias[do0 + r]) << 16)
                      + bits2f(((u32)anchor[(size_t)(nn * C_ + do0 + r) * HW_ + p]) << 16);
            outp[(size_t)(nn * C_ + do0 + r) * HW_ + p] = __float2bfloat16(res);
        }
    }
}

// ================= round-1 fallback (known-good, both dtypes, no ws) =========
template<bool BF16>
__global__ __launch_bounds__(256) void traj_fallback(
    const void* __restrict__ curr, const void* __restrict__ idxf,
    const void* __restrict__ anchor, const void* __restrict__ s1,
    const void* __restrict__ s2, const void* __restrict__ s3,
    const void* __restrict__ loc, const void* __restrict__ pw,
    const void* __restrict__ pb, const void* __restrict__ fw,
    const void* __restrict__ fb, void* __restrict__ outp,
    const int* __restrict__ flag, int enable_bf16)
{
    if (BF16 && !enable_bf16) return;
    if ((*flag != 0) != BF16) return;

    __shared__ __align__(16) float s_u[P_ * CATP_];
    __shared__ __align__(16) float s_mid[P_][100];
    __shared__ int   s_lin[T_][P_];
    __shared__ float s_red[P_][8];
    __shared__ float s_best[P_][HEAD_];
    __shared__ int   s_bidx[P_][HEAD_];
    __shared__ float s_inv[P_];

#define S_Q(pp, ch)  s_u[(pp) * QP_ + (ch)]
#define S_K(pp, ch)  s_u[3104 + (pp) * QP_ + (ch)]
#define S_CAT(pp, d) s_u[(pp) * CATP_ + (d)]

    const int tid = threadIdx.x;
    const int b  = blockIdx.x;
    const int nn = b / (HW_ / P_);
    const int p0 = (b - nn * (HW_ / P_)) * P_;

    if (tid < T_ * P_) {
        int t = tid / P_, pp = tid - t * P_;
        int p = p0 + pp;
        float x = ld1<BF16>(loc, (nn * 2 * T_ + 2 * t    ) * HW_ + p);
        float y = ld1<BF16>(loc, (nn * 2 * T_ + 2 * t + 1) * HW_ + p);
        float gx = 2.0f * x / 95.0f - 1.0f;
        float gy = 2.0f * y / 95.0f - 1.0f;
        float fx = (gx + 1.0f) * 0.5f * 95.0f;
        float fy = (gy + 1.0f) * 0.5f * 95.0f;
        float ix = rintf(fx), iy = rintf(fy);
        bool v = (ix >= 0.0f) && (ix <= 95.0f) && (iy >= 0.0f) && (iy <= 95.0f);
        s_lin[t][pp] = v ? ((int)iy * W_ + (int)ix) : -1;
    }
    if (tid < P_ * HEAD_) { s_best[tid >> 2][tid & 3] = -3.0e38f; s_bidx[tid >> 2][tid & 3] = 0; }

    for (int i = tid; i < C_ * P_; i += 256) {
        int ch = i / P_, pp = i - ch * P_;
        S_Q(pp, ch) = ld1<BF16>(curr, (nn * C_ + ch) * HW_ + p0 + pp);
    }
    __syncthreads();
    {
        int pp = tid >> 3, j = tid & 7;
        float s = 0.f;
        #pragma unroll
        for (int k = 0; k < 12; ++k) { float v = S_Q(pp, j * 12 + k); s += v * v; }
        s_red[pp][j] = s;
    }
    __syncthreads();
    if (tid < P_) {
        float s = 0.f;
        #pragma unroll
        for (int j = 0; j < 8; ++j) s += s_red[tid][j];
        s_inv[tid] = 1.0f / fmaxf(sqrtf(s), 1e-12f);
    }
    __syncthreads();
    for (int i = tid; i < C_ * P_; i += 256) {
        int ch = i / P_, pp = i - ch * P_;
        S_Q(pp, ch) *= s_inv[pp];
    }

    for (int t = 0; t < T_; ++t) {
        __syncthreads();
        for (int i = tid; i < C_ * P_; i += 256) {
            int ch = i / P_, pp = i - ch * P_;
            int lin = s_lin[t][pp];
            S_K(pp, ch) = (lin >= 0) ? ld1<BF16>(idxf, ((nn * T_ + t) * C_ + ch) * HW_ + lin) : 0.0f;
        }
        __syncthreads();
        {
            int pp = tid >> 3, j = tid & 7;
            float s = 0.f;
            #pragma unroll
            for (int k = 0; k < 12; ++k) { float v = S_K(pp, j * 12 + k); s += v * v; }
            s_red[pp][j] = s;
        }
        __syncthreads();
        if (tid < P_) {
            float s = 0.f;
            #pragma unroll
            for (int j = 0; j < 8; ++j) s += s_red[tid][j];
            s_inv[tid] = 1.0f / fmaxf(sqrtf(s), 1e-12f);
        }
        __syncthreads();
        if (tid < P_ * HEAD_) {
            int pp = tid >> 2, h = tid & 3;
            float s = 0.f;
            #pragma unroll
            for (int d = 0; d < HD_; ++d) s += S_K(pp, h * HD_ + d) * S_Q(pp, h * HD_ + d);
            s *= s_inv[pp];
            if (s > s_best[pp][h]) { s_best[pp][h] = s; s_bidx[pp][h] = t; }
        }
    }
    __syncthreads();

    for (int i = tid; i < C3_ * P_; i += 256) {
        int pp = i / C3_, d = i - pp * C3_;
        int set = d / C_, ch = d - set * C_;
        int h = ch / HD_;
        int bt = s_bidx[pp][h];
        int lin = s_lin[bt][pp];
        float v = 0.f;
        if (lin >= 0) {
            const void* sp = (set == 0) ? s1 : (set == 1) ? s2 : s3;
            v = ld1<BF16>(sp, ((nn * T_ + bt) * C_ + ch) * HW_ + lin);
        }
        S_CAT(pp, d) = v;
    }
    __syncthreads();

    for (int u = tid; u < 24 * P_; u += 256) {
        int cog = u / P_, pp = u - cog * P_;
        int co0 = cog * 4;
        float a0 = 0.f, a1 = 0.f, a2 = 0.f, a3 = 0.f;
        for (int d = 0; d < C3_; d += 4) {
            const float4 cv = *((const float4*)&S_CAT(pp, d));
            float w[4];
            ld4w<BF16>(fw, (co0 + 0) * C3_ + d, w);
            a0 += w[0] * cv.x + w[1] * cv.y + w[2] * cv.z + w[3] * cv.w;
            ld4w<BF16>(fw, (co0 + 1) * C3_ + d, w);
            a1 += w[0] * cv.x + w[1] * cv.y + w[2] * cv.z + w[3] * cv.w;
            ld4w<BF16>(fw, (co0 + 2) * C3_ + d, w);
            a2 += w[0] * cv.x + w[1] * cv.y + w[2] * cv.z + w[3] * cv.w;
            ld4w<BF16>(fw, (co0 + 3) * C3_ + d, w);
            a3 += w[0] * cv.x + w[1] * cv.y + w[2] * cv.z + w[3] * cv.w;
        }
        float soft = s_best[pp][co0 / HD_];
        s_mid[pp][co0 + 0] = (a0 + ld1<BF16>(fb, co0 + 0)) * soft;
        s_mid[pp][co0 + 1] = (a1 + ld1<BF16>(fb, co0 + 1)) * soft;
        s_mid[pp][co0 + 2] = (a2 + ld1<BF16>(fb, co0 + 2)) * soft;
        s_mid[pp][co0 + 3] = (a3 + ld1<BF16>(fb, co0 + 3)) * soft;
    }
    __syncthreads();

    for (int u = tid; u < 24 * P_; u += 256) {
        int dog = u / P_, pp = u - dog * P_;
        int do0 = dog * 4;
        float a0 = 0.f, a1 = 0.f, a2 = 0.f, a3 = 0.f;
        for (int c = 0; c < C_; c += 4) {
            const float4 mv = *((const float4*)&s_mid[pp][c]);
            float w[4];
            ld4w<BF16>(pw, (do0 + 0) * C_ + c, w);
            a0 += w[0] * mv.x + w[1] * mv.y + w[2] * mv.z + w[3] * mv.w;
            ld4w<BF16>(pw, (do0 + 1) * C_ + c, w);
            a1 += w[0] * mv.x + w[1] * mv.y + w[2] * mv.z + w[3] * mv.w;
            ld4w<BF16>(pw, (do0 + 2) * C_ + c, w);
            a2 += w[0] * mv.x + w[1] * mv.y + w[2] * mv.z + w[3] * mv.w;
            ld4w<BF16>(pw, (do0 + 3) * C_ + c, w);
            a3 += w[0] * mv.x + w[1] * mv.y + w[2] * mv.z + w[3] * mv.w;
        }
        int p = p0 + pp;
        float r0 = a0 + ld1<BF16>(pb, do0 + 0) + ld1<BF16>(anchor, (nn * C_ + do0 + 0) * HW_ + p);
        float r1 = a1 + ld1<BF16>(pb, do0 + 1) + ld1<BF16>(anchor, (nn * C_ + do0 + 1) * HW_ + p);
        float r2 = a2 + ld1<BF16>(pb, do0 + 2) + ld1<BF16>(anchor, (nn * C_ + do0 + 2) * HW_ + p);
        float r3 = a3 + ld1<BF16>(pb, do0 + 3) + ld1<BF16>(anchor, (nn * C_ + do0 + 3) * HW_ + p);
        st1<BF16>(outp, (nn * C_ + do0 + 0) * HW_ + p, r0);
        st1<BF16>(outp, (nn * C_ + do0 + 1) * HW_ + p, r1);
        st1<BF16>(outp, (nn * C_ + do0 + 2) * HW_ + p, r2);
        st1<BF16>(outp, (nn * C_ + do0 + 3) * HW_ + p, r3);
    }
#undef S_Q
#undef S_K
#undef S_CAT
}

extern "C" void kernel_launch(void* const* d_in, const int* in_sizes, int n_in,
                              void* d_out, int out_size, void* d_ws, size_t ws_size,
                              hipStream_t stream) {
    (void)in_sizes; (void)n_in; (void)out_size;
    int* flag = (int*)d_ws;
    u16* wsb = (u16*)((char*)d_ws + 256);
    detect_dtype_kernel<<<1, 64, 0, stream>>>((const u32*)d_in[0], flag);

    const u16* curr  = (const u16*)d_in[0];
    const u16* idxf  = (const u16*)d_in[1];
    const u16* anch  = (const u16*)d_in[2];
    const u16* s1    = (const u16*)d_in[3];
    const u16* s2    = (const u16*)d_in[4];
    const u16* s3    = (const u16*)d_in[5];
    const u16* loc   = (const u16*)d_in[6];
    const u16* pw    = (const u16*)d_in[7];
    const u16* pbias = (const u16*)d_in[8];
    const u16* fw    = (const u16*)d_in[9];
    const u16* fbias = (const u16*)d_in[10];
    __hip_bfloat16* outb = (__hip_bfloat16*)d_out;

    const size_t base  = 256;
    const size_t full4 = 4 * 2 * PERN_ * 2;   // 99.1 MB  (4 tensors, both n)
    const size_t half4 = 4 * PERN_ * 2;       // 49.5 MB  (4 tensors, one n)
    const size_t idx2  = 2 * PERN_ * 2;       // 24.8 MB  (idx only, both n)
    const size_t idx1  = PERN_ * 2;           // 12.4 MB  (idx only, one n)

    int used_opt = 0;
    if (ws_size >= base + full4) {
        transpose_kernel<<<4 * 2 * T_ * 36, 256, 0, stream>>>(idxf, s1, s2, s3, wsb, flag, 4, 0, 2);
        traj_opt<1><<<2 * 288, 256, 0, stream>>>(curr, anch, loc, pw, pbias, fw, fbias, outb,
                                                 wsb, s1, s2, s3, flag, 0, 2);
        used_opt = 1;
    } else if (ws_size >= base + half4) {
        for (int nn = 0; nn < 2; ++nn) {
            transpose_kernel<<<4 * 1 * T_ * 36, 256, 0, stream>>>(idxf, s1, s2, s3, wsb, flag, 4, nn, 1);
            traj_opt<1><<<288, 256, 0, stream>>>(curr, anch, loc, pw, pbias, fw, fbias, outb,
                                                 wsb, s1, s2, s3, flag, nn, 1);
        }
        used_opt = 1;
    } else if (ws_size >= base + idx2) {
        transpose_kernel<<<1 * 2 * T_ * 36, 256, 0, stream>>>(idxf, s1, s2, s3, wsb, flag, 1, 0, 2);
        traj_opt<0><<<2 * 288, 256, 0, stream>>>(curr, anch, loc, pw, pbias, fw, fbias, outb,
                                                 wsb, s1, s2, s3, flag, 0, 2);
        used_opt = 1;
    } else if (ws_size >= base + idx1) {
        for (int nn = 0; nn < 2; ++nn) {
            transpose_kernel<<<1 * 1 * T_ * 36, 256, 0, stream>>>(idxf, s1, s2, s3, wsb, flag, 1, nn, 1);
            traj_opt<0><<<288, 256, 0, stream>>>(curr, anch, loc, pw, pbias, fw, fbias, outb,
                                                 wsb, s1, s2, s3, flag, nn, 1);
        }
        used_opt = 1;
    }

    // bf16 fallback only when no opt tier ran; f32 fallback always (flag-gated).
    traj_fallback<true><<<NBLK_, 256, 0, stream>>>(d_in[0], d_in[1], d_in[2], d_in[3],
                                                   d_in[4], d_in[5], d_in[6], d_in[7],
                                                   d_in[8], d_in[9], d_in[10], d_out, flag,
                                                   used_opt ? 0 : 1);
    traj_fallback<false><<<NBLK_, 256, 0, stream>>>(d_in[0], d_in[1], d_in[2], d_in[3],
                                                    d_in[4], d_in[5], d_in[6], d_in[7],
                                                    d_in[8], d_in[9], d_in[10], d_out, flag, 1);
}

// Round 4
// 494.321 us; speedup vs baseline: 1.0081x; 1.0081x over previous
//
#include <hip/hip_runtime.h>
#include <hip/hip_bf16.h>

#define N_    2
#define T_    7
#define C_    96
#define H_    96
#define W_    96
#define HW_   9216
#define HEAD_ 4
#define HD_   24
#define C3_   288
#define PB_   8                      // pixels per block (v3)
#define NBLK3_ (N_ * (HW_ / PB_))    // 2304
#define CATP_ 296                    // padded cat row (u16) — conflict-free b128
#define QP_   97
#define CATF_ 292

typedef unsigned int u32;
typedef unsigned short u16;

__device__ __forceinline__ float bits2f(u32 b) {
    union { u32 u; float f; } x; x.u = b; return x.f;
}
__device__ __forceinline__ float b2f(u16 v) { return bits2f(((u32)v) << 16); }

template<bool BF16>
__device__ __forceinline__ float ld1(const void* p, int i) {
    if constexpr (BF16) return b2f(((const u16*)p)[i]);
    else                return ((const float*)p)[i];
}
template<bool BF16>
__device__ __forceinline__ void ld4w(const void* p, int i, float w[4]) {
    if constexpr (BF16) {
        const uint2 u = ((const uint2*)p)[i >> 2];
        w[0] = bits2f(u.x << 16); w[1] = bits2f(u.x & 0xFFFF0000u);
        w[2] = bits2f(u.y << 16); w[3] = bits2f(u.y & 0xFFFF0000u);
    } else {
        const float4 v = *((const float4*)((const float*)p + i));
        w[0] = v.x; w[1] = v.y; w[2] = v.z; w[3] = v.w;
    }
}
template<bool BF16>
__device__ __forceinline__ void st1(void* p, int i, float v) {
    if constexpr (BF16) ((__hip_bfloat16*)p)[i] = __float2bfloat16(v);
    else                ((float*)p)[i] = v;
}
__device__ __forceinline__ void unpack8(uint4 u, float f[8]) {
    f[0] = bits2f(u.x << 16); f[1] = bits2f(u.x & 0xFFFF0000u);
    f[2] = bits2f(u.y << 16); f[3] = bits2f(u.y & 0xFFFF0000u);
    f[4] = bits2f(u.z << 16); f[5] = bits2f(u.z & 0xFFFF0000u);
    f[6] = bits2f(u.w << 16); f[7] = bits2f(u.w & 0xFFFF0000u);
}

// ---- dtype detector (bf16 vs f32) ----
__global__ void detect_dtype_kernel(const u32* __restrict__ w, int* __restrict__ flag) {
    u32 x = w[threadIdx.x];
    u32 f = x & 0x7FFFu;
    int inwin = (f >= 0x3A00u) && (f <= 0x4200u);
    unsigned long long m = __ballot(inwin);
    if (threadIdx.x == 0) flag[0] = (__popcll(m) >= 40) ? 1 : 0;
}

// ============ v3: MLP-maximized fused kernel (bf16, no workspace) ============
// grid = 2304 blocks x 256 threads; 8 pixels/block.
// Correlation: thread = (pixel, head, frame); 24 independent scalar gathers each.
__global__ __launch_bounds__(256) void traj_v3(
    const u16* __restrict__ curr, const u16* __restrict__ idxf,
    const u16* __restrict__ anchor, const u16* __restrict__ s1,
    const u16* __restrict__ s2, const u16* __restrict__ s3,
    const u16* __restrict__ loc, const u16* __restrict__ pw,
    const u16* __restrict__ pbias, const u16* __restrict__ fw,
    const u16* __restrict__ fbias, __hip_bfloat16* __restrict__ outp,
    const int* __restrict__ flag)
{
    if (*flag == 0) return;

    __shared__ int   s_lin[T_][PB_];
    __shared__ float s_soft[PB_][HEAD_];
    __shared__ int   s_bidx[PB_][HEAD_];
    __shared__ __align__(16) u16   s_cat[PB_][CATP_];   // 4736 B
    __shared__ __align__(16) float s_mid[PB_][100];     // 3200 B

    const int tid = threadIdx.x;
    const int b   = blockIdx.x;
    const int nn  = b / (HW_ / PB_);
    const int p0  = (b - nn * (HW_ / PB_)) * PB_;

    // ---- nearest-sample indices (exact reference f32 op sequence) ----
    if (tid < T_ * PB_) {
        int t = tid >> 3, pp = tid & 7;
        int p = p0 + pp;
        float x = b2f(loc[(nn * 2 * T_ + 2 * t    ) * HW_ + p]);
        float y = b2f(loc[(nn * 2 * T_ + 2 * t + 1) * HW_ + p]);
        float gx = 2.0f * x / 95.0f - 1.0f;
        float gy = 2.0f * y / 95.0f - 1.0f;
        float fx = (gx + 1.0f) * 0.5f * 95.0f;
        float fy = (gy + 1.0f) * 0.5f * 95.0f;
        float ix = rintf(fx), iy = rintf(fy);
        bool v = (ix >= 0.0f) && (ix <= 95.0f) && (iy >= 0.0f) && (iy <= 95.0f);
        s_lin[t][pp] = v ? ((int)iy * W_ + (int)ix) : -1;
    }
    __syncthreads();

    // ---- correlation: lane = (pg, tt, hh) ----
    const int pg = tid >> 5;          // pixel in block, 0..7
    const int l  = tid & 31;
    const int tt = l >> 2;            // frame 0..7 (7 = idle)
    const int hh = l & 3;             // head
    const int p  = p0 + pg;

    // q fragment (redundant across tt lanes — broadcast loads, cheap)
    float q[HD_];
    float ssqq = 0.f;
    {
        const u16* qbase = curr + ((size_t)(nn * C_ + hh * HD_)) * HW_ + p;
        #pragma unroll
        for (int j = 0; j < HD_; ++j) {
            float v = b2f(qbase[(size_t)j * HW_]);
            q[j] = v; ssqq += v * v;
        }
    }
    ssqq += __shfl_xor(ssqq, 1);     // full-c norm: sum over 4 heads (quad)
    ssqq += __shfl_xor(ssqq, 2);
    const float qinv = 1.0f / fmaxf(sqrtf(ssqq), 1e-12f);

    float score = -3.0e38f;
    int   myt   = tt;
    {
        float dot = 0.f, ssk = 0.f;
        if (tt < T_) {
            int lin = s_lin[tt][pg];
            if (lin >= 0) {
                const u16* kbase = idxf + ((size_t)((nn * T_ + tt) * C_ + hh * HD_)) * HW_ + lin;
                #pragma unroll
                for (int j = 0; j < HD_; ++j) {
                    float v = b2f(kbase[(size_t)j * HW_]);
                    dot += v * q[j]; ssk += v * v;
                }
            }
        }
        ssk += __shfl_xor(ssk, 1);   // sum over 4 heads (quad, same tt)
        ssk += __shfl_xor(ssk, 2);
        if (tt < T_) {
            float kinv = 1.0f / fmaxf(sqrtf(ssk), 1e-12f);
            score = dot * qinv * kinv;
        }
    }
    // max/argmax over tt (xor 4,8,16 — h and pg bits preserved); first-max tie-break
    #pragma unroll
    for (int m = 4; m <= 16; m <<= 1) {
        float os = __shfl_xor(score, m);
        int   ot = __shfl_xor(myt, m);
        if (os > score || (os == score && ot < myt)) { score = os; myt = ot; }
    }
    if (tt == 0) { s_soft[pg][hh] = score; s_bidx[pg][hh] = myt; }
    __syncthreads();

    // ---- pick: gather winning frames into cat tile (8 px * 288) ----
    for (int i = tid; i < PB_ * C3_; i += 256) {       // 9 exact iterations
        int pp = i / C3_, d = i - pp * C3_;
        int set = d / C_, ch = d - set * C_;
        int h = ch / HD_;
        int bt = s_bidx[pp][h];
        int lin = s_lin[bt][pp];
        u16 v = 0;
        if (lin >= 0) {
            const u16* sp = (set == 0) ? s1 : (set == 1) ? s2 : s3;
            v = sp[((size_t)((nn * T_ + bt) * C_ + ch)) * HW_ + lin];
        }
        s_cat[pp][d] = v;
    }
    __syncthreads();

    // ---- fusion GEMV (96 x 288) + bias, scaled by per-head max score ----
    #pragma unroll
    for (int r = 0; r < 3; ++r) {
        int co = r * 32 + (tid >> 3);
        int pp = tid & 7;
        float acc = 0.f;
        const u16* wrow = fw + (size_t)co * C3_;
        for (int d = 0; d < C3_; d += 8) {
            float cv[8], wv[8];
            unpack8(*((const uint4*)&s_cat[pp][d]), cv);
            unpack8(*((const uint4*)(wrow + d)), wv);
            #pragma unroll
            for (int j = 0; j < 8; ++j) acc += wv[j] * cv[j];
        }
        float soft = s_soft[pp][co / HD_];
        s_mid[pp][co] = (acc + b2f(fbias[co])) * soft;
    }
    __syncthreads();

    // ---- proj GEMV (96 x 96) + bias + anchor, store ----
    #pragma unroll
    for (int r = 0; r < 3; ++r) {
        int co = r * 32 + (tid >> 3);
        int pp = tid & 7;
        float acc = 0.f;
        const u16* wrow = pw + (size_t)co * C_;
        for (int c = 0; c < C_; c += 8) {
            const float4 m0 = *((const float4*)&s_mid[pp][c]);
            const float4 m1 = *((const float4*)&s_mid[pp][c + 4]);
            float wv[8];
            unpack8(*((const uint4*)(wrow + c)), wv);
            acc += wv[0] * m0.x + wv[1] * m0.y + wv[2] * m0.z + wv[3] * m0.w
                 + wv[4] * m1.x + wv[5] * m1.y + wv[6] * m1.z + wv[7] * m1.w;
        }
        int pq = p0 + pp;
        float res = acc + b2f(pbias[co]) + b2f(anchor[((size_t)(nn * C_ + co)) * HW_ + pq]);
        outp[((size_t)(nn * C_ + co)) * HW_ + pq] = __float2bfloat16(res);
    }
}

// ================= f32 fallback (flag-gated; known-good structure) =========
template<bool BF16>
__global__ __launch_bounds__(256) void traj_fallback(
    const void* __restrict__ curr, const void* __restrict__ idxf,
    const void* __restrict__ anchor, const void* __restrict__ s1,
    const void* __restrict__ s2, const void* __restrict__ s3,
    const void* __restrict__ loc, const void* __restrict__ pw,
    const void* __restrict__ pb, const void* __restrict__ fw,
    const void* __restrict__ fb, void* __restrict__ outp,
    const int* __restrict__ flag)
{
    if ((*flag != 0) != BF16) return;

    __shared__ __align__(16) float s_u[32 * CATF_];
    __shared__ __align__(16) float s_mid[32][100];
    __shared__ int   s_lin[T_][32];
    __shared__ float s_red[32][8];
    __shared__ float s_best[32][HEAD_];
    __shared__ int   s_bidx[32][HEAD_];
    __shared__ float s_inv[32];

#define S_Q(pp, ch)  s_u[(pp) * QP_ + (ch)]
#define S_K(pp, ch)  s_u[3104 + (pp) * QP_ + (ch)]
#define S_CAT(pp, d) s_u[(pp) * CATF_ + (d)]

    const int tid = threadIdx.x;
    const int b  = blockIdx.x;
    const int nn = b / (HW_ / 32);
    const int p0 = (b - nn * (HW_ / 32)) * 32;

    if (tid < T_ * 32) {
        int t = tid / 32, pp = tid - t * 32;
        int p = p0 + pp;
        float x = ld1<BF16>(loc, (nn * 2 * T_ + 2 * t    ) * HW_ + p);
        float y = ld1<BF16>(loc, (nn * 2 * T_ + 2 * t + 1) * HW_ + p);
        float gx = 2.0f * x / 95.0f - 1.0f;
        float gy = 2.0f * y / 95.0f - 1.0f;
        float fx = (gx + 1.0f) * 0.5f * 95.0f;
        float fy = (gy + 1.0f) * 0.5f * 95.0f;
        float ix = rintf(fx), iy = rintf(fy);
        bool v = (ix >= 0.0f) && (ix <= 95.0f) && (iy >= 0.0f) && (iy <= 95.0f);
        s_lin[t][pp] = v ? ((int)iy * W_ + (int)ix) : -1;
    }
    if (tid < 32 * HEAD_) { s_best[tid >> 2][tid & 3] = -3.0e38f; s_bidx[tid >> 2][tid & 3] = 0; }

    for (int i = tid; i < C_ * 32; i += 256) {
        int ch = i / 32, pp = i - ch * 32;
        S_Q(pp, ch) = ld1<BF16>(curr, (nn * C_ + ch) * HW_ + p0 + pp);
    }
    __syncthreads();
    {
        int pp = tid >> 3, j = tid & 7;
        float s = 0.f;
        #pragma unroll
        for (int k = 0; k < 12; ++k) { float v = S_Q(pp, j * 12 + k); s += v * v; }
        s_red[pp][j] = s;
    }
    __syncthreads();
    if (tid < 32) {
        float s = 0.f;
        #pragma unroll
        for (int j = 0; j < 8; ++j) s += s_red[tid][j];
        s_inv[tid] = 1.0f / fmaxf(sqrtf(s), 1e-12f);
    }
    __syncthreads();
    for (int i = tid; i < C_ * 32; i += 256) {
        int ch = i / 32, pp = i - ch * 32;
        S_Q(pp, ch) *= s_inv[pp];
    }

    for (int t = 0; t < T_; ++t) {
        __syncthreads();
        for (int i = tid; i < C_ * 32; i += 256) {
            int ch = i / 32, pp = i - ch * 32;
            int lin = s_lin[t][pp];
            S_K(pp, ch) = (lin >= 0) ? ld1<BF16>(idxf, ((nn * T_ + t) * C_ + ch) * HW_ + lin) : 0.0f;
        }
        __syncthreads();
        {
            int pp = tid >> 3, j = tid & 7;
            float s = 0.f;
            #pragma unroll
            for (int k = 0; k < 12; ++k) { float v = S_K(pp, j * 12 + k); s += v * v; }
            s_red[pp][j] = s;
        }
        __syncthreads();
        if (tid < 32) {
            float s = 0.f;
            #pragma unroll
            for (int j = 0; j < 8; ++j) s += s_red[tid][j];
            s_inv[tid] = 1.0f / fmaxf(sqrtf(s), 1e-12f);
        }
        __syncthreads();
        if (tid < 32 * HEAD_) {
            int pp = tid >> 2, h = tid & 3;
            float s = 0.f;
            #pragma unroll
            for (int d = 0; d < HD_; ++d) s += S_K(pp, h * HD_ + d) * S_Q(pp, h * HD_ + d);
            s *= s_inv[pp];
            if (s > s_best[pp][h]) { s_best[pp][h] = s; s_bidx[pp][h] = t; }
        }
    }
    __syncthreads();

    for (int i = tid; i < C3_ * 32; i += 256) {
        int pp = i / C3_, d = i - pp * C3_;
        int set = d / C_, ch = d - set * C_;
        int h = ch / HD_;
        int bt = s_bidx[pp][h];
        int lin = s_lin[bt][pp];
        float v = 0.f;
        if (lin >= 0) {
            const void* sp = (set == 0) ? s1 : (set == 1) ? s2 : s3;
            v = ld1<BF16>(sp, ((nn * T_ + bt) * C_ + ch) * HW_ + lin);
        }
        S_CAT(pp, d) = v;
    }
    __syncthreads();

    for (int u = tid; u < 24 * 32; u += 256) {
        int cog = u / 32, pp = u - cog * 32;
        int co0 = cog * 4;
        float a0 = 0.f, a1 = 0.f, a2 = 0.f, a3 = 0.f;
        for (int d = 0; d < C3_; d += 4) {
            const float4 cv = *((const float4*)&S_CAT(pp, d));
            float w[4];
            ld4w<BF16>(fw, (co0 + 0) * C3_ + d, w);
            a0 += w[0] * cv.x + w[1] * cv.y + w[2] * cv.z + w[3] * cv.w;
            ld4w<BF16>(fw, (co0 + 1) * C3_ + d, w);
            a1 += w[0] * cv.x + w[1] * cv.y + w[2] * cv.z + w[3] * cv.w;
            ld4w<BF16>(fw, (co0 + 2) * C3_ + d, w);
            a2 += w[0] * cv.x + w[1] * cv.y + w[2] * cv.z + w[3] * cv.w;
            ld4w<BF16>(fw, (co0 + 3) * C3_ + d, w);
            a3 += w[0] * cv.x + w[1] * cv.y + w[2] * cv.z + w[3] * cv.w;
        }
        float soft = s_best[pp][co0 / HD_];
        s_mid[pp][co0 + 0] = (a0 + ld1<BF16>(fb, co0 + 0)) * soft;
        s_mid[pp][co0 + 1] = (a1 + ld1<BF16>(fb, co0 + 1)) * soft;
        s_mid[pp][co0 + 2] = (a2 + ld1<BF16>(fb, co0 + 2)) * soft;
        s_mid[pp][co0 + 3] = (a3 + ld1<BF16>(fb, co0 + 3)) * soft;
    }
    __syncthreads();

    for (int u = tid; u < 24 * 32; u += 256) {
        int dog = u / 32, pp = u - dog * 32;
        int do0 = dog * 4;
        float a0 = 0.f, a1 = 0.f, a2 = 0.f, a3 = 0.f;
        for (int c = 0; c < C_; c += 4) {
            const float4 mv = *((const float4*)&s_mid[pp][c]);
            float w[4];
            ld4w<BF16>(pw, (do0 + 0) * C_ + c, w);
            a0 += w[0] * mv.x + w[1] * mv.y + w[2] * mv.z + w[3] * mv.w;
            ld4w<BF16>(pw, (do0 + 1) * C_ + c, w);
            a1 += w[0] * mv.x + w[1] * mv.y + w[2] * mv.z + w[3] * mv.w;
            ld4w<BF16>(pw, (do0 + 2) * C_ + c, w);
            a2 += w[0] * mv.x + w[1] * mv.y + w[2] * mv.z + w[3] * mv.w;
            ld4w<BF16>(pw, (do0 + 3) * C_ + c, w);
            a3 += w[0] * mv.x + w[1] * mv.y + w[2] * mv.z + w[3] * mv.w;
        }
        int p = p0 + pp;
        float r0 = a0 + ld1<BF16>(pb, do0 + 0) + ld1<BF16>(anchor, (nn * C_ + do0 + 0) * HW_ + p);
        float r1 = a1 + ld1<BF16>(pb, do0 + 1) + ld1<BF16>(anchor, (nn * C_ + do0 + 1) * HW_ + p);
        float r2 = a2 + ld1<BF16>(pb, do0 + 2) + ld1<BF16>(anchor, (nn * C_ + do0 + 2) * HW_ + p);
        float r3 = a3 + ld1<BF16>(pb, do0 + 3) + ld1<BF16>(anchor, (nn * C_ + do0 + 3) * HW_ + p);
        st1<BF16>(outp, (nn * C_ + do0 + 0) * HW_ + p, r0);
        st1<BF16>(outp, (nn * C_ + do0 + 1) * HW_ + p, r1);
        st1<BF16>(outp, (nn * C_ + do0 + 2) * HW_ + p, r2);
        st1<BF16>(outp, (nn * C_ + do0 + 3) * HW_ + p, r3);
    }
#undef S_Q
#undef S_K
#undef S_CAT
}

extern "C" void kernel_launch(void* const* d_in, const int* in_sizes, int n_in,
                              void* d_out, int out_size, void* d_ws, size_t ws_size,
                              hipStream_t stream) {
    (void)in_sizes; (void)n_in; (void)out_size; (void)ws_size;
    int* flag = (int*)d_ws;
    detect_dtype_kernel<<<1, 64, 0, stream>>>((const u32*)d_in[0], flag);

    // bf16 path: high-MLP fused kernel (no workspace needed beyond the flag)
    traj_v3<<<NBLK3_, 256, 0, stream>>>((const u16*)d_in[0], (const u16*)d_in[1],
                                        (const u16*)d_in[2], (const u16*)d_in[3],
                                        (const u16*)d_in[4], (const u16*)d_in[5],
                                        (const u16*)d_in[6], (const u16*)d_in[7],
                                        (const u16*)d_in[8], (const u16*)d_in[9],
                                        (const u16*)d_in[10], (__hip_bfloat16*)d_out, flag);
    // f32 path (flag-gated; returns immediately when input is bf16)
    traj_fallback<false><<<N_ * (HW_ / 32), 256, 0, stream>>>(
        d_in[0], d_in[1], d_in[2], d_in[3], d_in[4], d_in[5], d_in[6], d_in[7],
        d_in[8], d_in[9], d_in[10], d_out, flag);
}